// Round 10
// baseline (405.824 us; speedup 1.0000x reference)
//
#include <hip/hip_runtime.h>
#include <cstdint>
#include <cstddef>

// Problem constants
#define D_    512
#define H_    4
#define DH_   128
#define FFN_  128
#define L_    4
#define B_    8
#define T_    1025
#define U_    1024
#define NSEG_ 256
#define R_    256
#define TOT_  1280            // R + U
#define M_    (B_*TOT_)       // 10240 rows
#define CH_   1536            // QKV channels

typedef __attribute__((ext_vector_type(8))) short bf16x8;
typedef __attribute__((ext_vector_type(4))) float f32x4;
typedef unsigned short u16;

__device__ __forceinline__ u16 f2bf(float f) {
  unsigned u = __builtin_bit_cast(unsigned, f);
  u += 0x7fff + ((u >> 16) & 1);           // round-to-nearest-even
  return (u16)(u >> 16);
}
__device__ __forceinline__ float bf2f(u16 h) {
  unsigned u = ((unsigned)h) << 16;
  return __builtin_bit_cast(float, u);
}

__device__ __forceinline__ void gload_lds16(const void* g, void* l) {
  __builtin_amdgcn_global_load_lds(
      (const __attribute__((address_space(1))) unsigned*)g,
      (__attribute__((address_space(3))) unsigned*)l, 16, 0, 0);
}

// ---------------------------------------------------------------------------
// one-shot weight conversion / packing:
//   WQKVb[l][1536][512] bf16  (rows 0-511 = Wq[l], 512-1535 = Wkv[l])
//   Wob, W1b, W2b bf16 straight copies;  bQKV[l][1536] fp32 (bq|bkv)
// ---------------------------------------------------------------------------
__global__ __launch_bounds__(256)
void cvt_all_k(const float* __restrict__ Wq, const float* __restrict__ Wkv,
               const float* __restrict__ Wo, const float* __restrict__ W1,
               const float* __restrict__ W2, const float* __restrict__ bq,
               const float* __restrict__ bkv,
               u16* __restrict__ WQKVb, u16* __restrict__ Wob,
               u16* __restrict__ W1b, u16* __restrict__ W2b,
               float* __restrict__ bQKV) {
  int i4 = blockIdx.x * 256 + threadIdx.x;
  if (i4 < 786432) {                        // WQKV: 3,145,728 elems
    int e = i4 * 4;
    int l = e / 786432;
    int rem = e - l * 786432;
    int n = rem >> 9, k = rem & 511;
    const float* src = (n < 512) ? (Wq + (size_t)l * 262144 + n * 512 + k)
                                 : (Wkv + (size_t)l * 524288 + (n - 512) * 512 + k);
    float4 v = *(const float4*)src;
    ushort4 o; o.x = f2bf(v.x); o.y = f2bf(v.y); o.z = f2bf(v.z); o.w = f2bf(v.w);
    *(ushort4*)(WQKVb + e) = o;
  } else if (i4 < 1048576) {                // Wo
    int e = (i4 - 786432) * 4;
    float4 v = *(const float4*)(Wo + e);
    ushort4 o; o.x = f2bf(v.x); o.y = f2bf(v.y); o.z = f2bf(v.z); o.w = f2bf(v.w);
    *(ushort4*)(Wob + e) = o;
  } else if (i4 < 1114112) {                // W1
    int e = (i4 - 1048576) * 4;
    float4 v = *(const float4*)(W1 + e);
    ushort4 o; o.x = f2bf(v.x); o.y = f2bf(v.y); o.z = f2bf(v.z); o.w = f2bf(v.w);
    *(ushort4*)(W1b + e) = o;
  } else if (i4 < 1179648) {                // W2
    int e = (i4 - 1114112) * 4;
    float4 v = *(const float4*)(W2 + e);
    ushort4 o; o.x = f2bf(v.x); o.y = f2bf(v.y); o.z = f2bf(v.z); o.w = f2bf(v.w);
    *(ushort4*)(W2b + e) = o;
  } else if (i4 < 1181184) {                // bias: 6144 elems
    int e = (i4 - 1179648) * 4;
    int l = e / 1536, n = e - l * 1536;
#pragma unroll
    for (int t = 0; t < 4; ++t) {
      int nn = n + t;
      bQKV[e + t] = (nn < 512) ? bq[l * 512 + nn] : bkv[l * 1024 + (nn - 512)];
    }
  }
}

// ---------------------------------------------------------------------------
// gather + LN-in(layer 0): builds X (fp32 residual) and LNbuf (bf16)
// ---------------------------------------------------------------------------
__global__ __launch_bounds__(256)
void gather_ln_k(const float* __restrict__ x, const float* __restrict__ g,
                 const float* __restrict__ bb, float* __restrict__ X,
                 u16* __restrict__ LNb) {
  int row = blockIdx.x;
  int tid = threadIdx.x;
  int b = row / TOT_, p = row % TOT_;
  int t = (p < R_) ? ((p < R_ - 1) ? 4 * (p + 1) : (T_ - 1)) : (p - R_);
  const float* xr = x + ((size_t)b * T_ + t) * D_;
  float e0 = xr[tid], e1 = xr[tid + 256];
  X[(size_t)row * D_ + tid] = e0;
  X[(size_t)row * D_ + tid + 256] = e1;
  float s = e0 + e1, ss = e0 * e0 + e1 * e1;
#pragma unroll
  for (int off = 32; off > 0; off >>= 1) {
    s  += __shfl_down(s, off);
    ss += __shfl_down(ss, off);
  }
  __shared__ float red[10];
  int wid = tid >> 6, lane = tid & 63;
  if (lane == 0) { red[wid] = s; red[4 + wid] = ss; }
  __syncthreads();
  if (tid == 0) {
    float S = red[0] + red[1] + red[2] + red[3];
    float SS = red[4] + red[5] + red[6] + red[7];
    float mu = S * (1.0f / D_);
    float var = SS * (1.0f / D_) - mu * mu;
    if (var < 0.f) var = 0.f;
    red[8] = mu; red[9] = rsqrtf(var + 1e-5f);
  }
  __syncthreads();
  float mu = red[8], rs = red[9];
  u16* yr = LNb + (size_t)row * D_;
  yr[tid]       = f2bf((e0 - mu) * rs * g[tid]       + bb[tid]);
  yr[tid + 256] = f2bf((e1 - mu) * rs * g[tid + 256] + bb[tid + 256]);
}

// ---------------------------------------------------------------------------
// bf16 MFMA GEMM, m97-style (128x128 tile, BK=32, 4 waves), XCD-swizzled.
// QKV projection: M=10240, N=1536, K=512. xcd=bid&7 owns 10 row-stripes
// x 12 col-blocks -> A chunk 1.28MB L2-resident per XCD.
// ---------------------------------------------------------------------------
#define GBK 32

__global__ __launch_bounds__(256)
void gemm_qkv(const u16* __restrict__ A, const u16* __restrict__ Bw,
              const float* __restrict__ bias, u16* __restrict__ Cout) {
  __shared__ __align__(16) u16 As[128 * GBK];
  __shared__ __align__(16) u16 Bs[128 * GBK];
  const int tid = threadIdx.x;
  const int wid = tid >> 6;
  const int lane = tid & 63;
  const int bid = blockIdx.x;
  const int xcd = bid & 7;
  const int t = bid >> 3;                 // 0..119
  const int cb = t % 12;
  const int rb = xcd * 10 + t / 12;
  const int bm = rb * 128;
  const int bn = cb * 128;
  const int wr = wid >> 1, wc = wid & 1;

  const int srow = tid >> 2;
  const int skoff = (tid & 3) << 3;

  f32x4 acc[4][4] = {};

  const u16* Ag0 = A  + (size_t)(bm + srow)      * D_ + skoff;
  const u16* Ag1 = A  + (size_t)(bm + 64 + srow) * D_ + skoff;
  const u16* Bg0 = Bw + (size_t)(bn + srow)      * D_ + skoff;
  const u16* Bg1 = Bw + (size_t)(bn + 64 + srow) * D_ + skoff;
  u16* AsW0 = &As[(size_t)(wid * 16)      * GBK];
  u16* AsW1 = &As[(size_t)(64 + wid * 16) * GBK];
  u16* BsW0 = &Bs[(size_t)(wid * 16)      * GBK];
  u16* BsW1 = &Bs[(size_t)(64 + wid * 16) * GBK];

  const int lrow = lane & 15;
  const int lko  = (lane >> 4) * 16;

  for (int k0 = 0; k0 < D_; k0 += GBK) {
    __syncthreads();
    gload_lds16(Ag0 + k0, AsW0);
    gload_lds16(Ag1 + k0, AsW1);
    gload_lds16(Bg0 + k0, BsW0);
    gload_lds16(Bg1 + k0, BsW1);
    __syncthreads();

    bf16x8 afrag[4], bfrag[4];
#pragma unroll
    for (int m = 0; m < 4; ++m) {
      int row = wr * 64 + m * 16 + lrow;
      afrag[m] = *(const bf16x8*)((const char*)As + row * (GBK * 2) + lko);
    }
#pragma unroll
    for (int n = 0; n < 4; ++n) {
      int col = wc * 64 + n * 16 + lrow;
      bfrag[n] = *(const bf16x8*)((const char*)Bs + col * (GBK * 2) + lko);
    }
#pragma unroll
    for (int m = 0; m < 4; ++m)
#pragma unroll
      for (int n = 0; n < 4; ++n)
        acc[m][n] = __builtin_amdgcn_mfma_f32_16x16x32_bf16(
            afrag[m], bfrag[n], acc[m][n], 0, 0, 0);
  }

  const int lcol  = lane & 15;
  const int lrow4 = (lane >> 4) * 4;
#pragma unroll
  for (int m = 0; m < 4; ++m) {
    int rowbase = bm + wr * 64 + m * 16 + lrow4;
#pragma unroll
    for (int n = 0; n < 4; ++n) {
      int col = bn + wc * 64 + n * 16 + lcol;
      float bv = bias[col];
#pragma unroll
      for (int j = 0; j < 4; ++j) {
        int row = rowbase + j;
        Cout[(size_t)row * CH_ + col] = f2bf(acc[m][n][j] + bv);
      }
    }
  }
}

// ---------------------------------------------------------------------------
// O-proj: pure N-tiled GEMM + residual, fp32 out (in-place X).
// Tile 64 rows x 128 cols, 4 waves (all share the 64 rows; wave w owns cols
// [w*32,+32)), BK=32. Grid 640 = 8 xcd x 4 cb x 20 row-halves -> 2.5
// blocks/CU (fixes the 1.25-blocks/CU imbalance of the 128x128 version).
// ---------------------------------------------------------------------------
__global__ __launch_bounds__(256)
void gemm_oproj(const u16* __restrict__ A, const u16* __restrict__ Bw,
                const float* __restrict__ bias, float* __restrict__ Xio) {
  __shared__ __align__(16) u16 As[64 * GBK];    // 4KB
  __shared__ __align__(16) u16 Bs[128 * GBK];   // 8KB
  const int tid = threadIdx.x;
  const int wid = tid >> 6;
  const int lane = tid & 63;
  const int bid = blockIdx.x;
  const int xcd = bid & 7;
  const int t = bid >> 3;                 // 0..79
  const int cb = t & 3;
  const int rbh = xcd * 20 + (t >> 2);    // 0..159
  const int bm = rbh * 64;
  const int bn = cb * 128;

  const int srow = tid >> 2;              // 0..63
  const int skoff = (tid & 3) << 3;

  f32x4 acc[4][2] = {};

  const u16* Ag  = A  + (size_t)(bm + srow)      * D_ + skoff;
  const u16* Bg0 = Bw + (size_t)(bn + srow)      * D_ + skoff;
  const u16* Bg1 = Bw + (size_t)(bn + 64 + srow) * D_ + skoff;
  u16* AsW  = &As[wid * 512];             // wave-uniform LDS bases
  u16* BsW0 = &Bs[wid * 512];
  u16* BsW1 = &Bs[2048 + wid * 512];

  const int lrow = lane & 15;
  const int lko  = (lane >> 4) * 16;

  for (int k0 = 0; k0 < D_; k0 += GBK) {
    __syncthreads();
    gload_lds16(Ag  + k0, AsW);
    gload_lds16(Bg0 + k0, BsW0);
    gload_lds16(Bg1 + k0, BsW1);
    __syncthreads();

    bf16x8 afrag[4], bfrag[2];
#pragma unroll
    for (int m = 0; m < 4; ++m) {
      int row = m * 16 + lrow;
      afrag[m] = *(const bf16x8*)((const char*)As + row * (GBK * 2) + lko);
    }
#pragma unroll
    for (int n = 0; n < 2; ++n) {
      int col = wid * 32 + n * 16 + lrow;
      bfrag[n] = *(const bf16x8*)((const char*)Bs + col * (GBK * 2) + lko);
    }
#pragma unroll
    for (int m = 0; m < 4; ++m)
#pragma unroll
      for (int n = 0; n < 2; ++n)
        acc[m][n] = __builtin_amdgcn_mfma_f32_16x16x32_bf16(
            afrag[m], bfrag[n], acc[m][n], 0, 0, 0);
  }

  const int lcol  = lane & 15;
  const int lrow4 = (lane >> 4) * 4;
#pragma unroll
  for (int m = 0; m < 4; ++m) {
    int rowbase = bm + m * 16 + lrow4;
#pragma unroll
    for (int n = 0; n < 2; ++n) {
      int col = bn + wid * 32 + n * 16 + lcol;
      float bv = bias[col];
#pragma unroll
      for (int j = 0; j < 4; ++j) {
        size_t idx = (size_t)(rowbase + j) * D_ + col;
        Xio[idx] = acc[m][n][j] + bv + Xio[idx];
      }
    }
  }
}

// ---------------------------------------------------------------------------
// FFN1 with LN_ff prologue: reads rc_out (fp32 X), computes LN per row
// in-register (16 lanes/row butterfly), stores normalized bf16 A-tile in
// LDS (XOR-swizzled (row&7)<<4, resident for whole K-loop), then
// H = relu(LN2 @ W1^T + b1). 16-row tiles, grid 640.
// ---------------------------------------------------------------------------
__global__ __launch_bounds__(256)
void ffn1_ln(const float* __restrict__ X,
             const float* __restrict__ gff, const float* __restrict__ bff,
             const u16* __restrict__ W1, const float* __restrict__ b1,
             u16* __restrict__ Hout) {
  __shared__ __align__(16) u16 Aln[16 * 512];   // 16KB, swizzled
  __shared__ __align__(16) u16 Bs[128 * 32];    // 8KB
  const int tid = threadIdx.x;
  const int wid = tid >> 6, lane = tid & 63;
  const int bm = blockIdx.x * 16;
  const int r  = tid >> 4;            // 0..15 row in tile
  const int jj = tid & 15;            // 16 lanes per row

  // ---- LN_ff in registers ----
  const float* xr = X + (size_t)(bm + r) * D_ + jj * 32;
  float v[32];
  float s = 0.f, ss = 0.f;
#pragma unroll
  for (int i = 0; i < 8; ++i) {
    float4 q = *(const float4*)(xr + i * 4);
    v[i * 4 + 0] = q.x; v[i * 4 + 1] = q.y;
    v[i * 4 + 2] = q.z; v[i * 4 + 3] = q.w;
    s  += q.x + q.y + q.z + q.w;
    ss += q.x * q.x + q.y * q.y + q.z * q.z + q.w * q.w;
  }
#pragma unroll
  for (int off = 1; off < 16; off <<= 1) {
    s  += __shfl_xor(s, off);
    ss += __shfl_xor(ss, off);
  }
  float mu = s * (1.0f / D_);
  float var = ss * (1.0f / D_) - mu * mu;
  if (var < 0.f) var = 0.f;
  float rs = rsqrtf(var + 1e-5f);

  char* Ab = (char*)Aln;
#pragma unroll
  for (int i = 0; i < 8; ++i) {
    int c0 = jj * 32 + i * 4;
    float4 g4 = *(const float4*)(gff + c0);
    float4 b4 = *(const float4*)(bff + c0);
    ushort4 o;
    o.x = f2bf((v[i * 4 + 0] - mu) * rs * g4.x + b4.x);
    o.y = f2bf((v[i * 4 + 1] - mu) * rs * g4.y + b4.y);
    o.z = f2bf((v[i * 4 + 2] - mu) * rs * g4.z + b4.z);
    o.w = f2bf((v[i * 4 + 3] - mu) * rs * g4.w + b4.w);
    int byteoff = (r * 1024 + c0 * 2) ^ ((r & 7) << 4);
    *(ushort4*)(Ab + byteoff) = o;
  }
  __syncthreads();

  // ---- K-loop: stage W1 only; A resident in LDS ----
  const int lrow = lane & 15;
  const int lko  = (lane >> 4) << 4;   // bytes
  const int l4 = lane >> 2;
  const int k8 = (lane & 3) << 3;
  f32x4 acc[2] = {};

  for (int k0 = 0; k0 < D_; k0 += 32) {
    if (k0) __syncthreads();
#pragma unroll
    for (int p = 0; p < 2; ++p) {
      int rowb = wid * 32 + p * 16 + l4;
      gload_lds16(W1 + (size_t)rowb * D_ + k0 + k8,
                  (char*)Bs + (wid * 32 + p * 16) * 64);
    }
    __syncthreads();
    bf16x8 af = *(const bf16x8*)((const char*)Aln +
                  ((lrow * 1024 + k0 * 2 + lko) ^ ((lrow & 7) << 4)));
    bf16x8 bf[2];
#pragma unroll
    for (int n = 0; n < 2; ++n)
      bf[n] = *(const bf16x8*)((const char*)Bs + (wid * 32 + n * 16 + lrow) * 64 + lko);
#pragma unroll
    for (int n = 0; n < 2; ++n)
      acc[n] = __builtin_amdgcn_mfma_f32_16x16x32_bf16(af, bf[n], acc[n], 0, 0, 0);
  }

  const int lcol = lane & 15;
  const int lr4 = (lane >> 4) * 4;
#pragma unroll
  for (int n = 0; n < 2; ++n) {
    int col = wid * 32 + n * 16 + lcol;
    float bv = b1[col];
#pragma unroll
    for (int j = 0; j < 4; ++j) {
      int row = bm + lr4 + j;
      Hout[(size_t)row * FFN_ + col] = f2bf(fmaxf(acc[n][j] + bv, 0.f));
    }
  }
}

// ---------------------------------------------------------------------------
// FFN2 + residual + LN_out (+ LN_in next). 16-row tiles (grid 640), K=128.
// MODE 1 (l<3): LN1 -> Xout fp32; LN2 -> OutBf bf16.
// MODE 2 (l=3): LN1 -> Xout fp32 only.
// ---------------------------------------------------------------------------
template <int MODE>
__global__ __launch_bounds__(256)
void gemm_row_ln(const u16* __restrict__ A, const u16* __restrict__ Bw,
                 const float* __restrict__ bias, const float* __restrict__ Rsd,
                 float* __restrict__ Xout,
                 const float* __restrict__ g1, const float* __restrict__ b1,
                 const float* __restrict__ g2, const float* __restrict__ b2,
                 u16* __restrict__ OutBf, int K) {
  __shared__ __align__(16) u16 As[16 * 32];
  __shared__ __align__(16) u16 Bs[512 * 32];
  __shared__ float wsum[4][16], wss[4][16], mu_s[16], rs_s[16];
  const int tid = threadIdx.x;
  const int wid = tid >> 6, lane = tid & 63;
  const int bm = blockIdx.x * 16;
  const int l4 = lane >> 2;
  const int k8 = (lane & 3) << 3;
  const int lrow = lane & 15;
  const int lko  = (lane >> 4) * 16;

  f32x4 acc[8] = {};

  const u16* Ag = A + (size_t)(bm + l4) * K + k8;

  for (int k0 = 0; k0 < K; k0 += 32) {
    __syncthreads();
    if (wid == 0)
      gload_lds16(Ag + k0, As);
#pragma unroll
    for (int p = 0; p < 8; ++p) {
      int row = wid * 128 + p * 16 + l4;
      gload_lds16(Bw + (size_t)row * K + k0 + k8,
                  (char*)Bs + (wid * 128 + p * 16) * 64);
    }
    __syncthreads();

    bf16x8 af = *(const bf16x8*)((const char*)As + lrow * 64 + lko);
    bf16x8 bf[8];
#pragma unroll
    for (int n = 0; n < 8; ++n)
      bf[n] = *(const bf16x8*)((const char*)Bs + (wid * 128 + n * 16 + lrow) * 64 + lko);
#pragma unroll
    for (int n = 0; n < 8; ++n)
      acc[n] = __builtin_amdgcn_mfma_f32_16x16x32_bf16(af, bf[n], acc[n], 0, 0, 0);
  }

  // ---- epilogue: bias + residual ----
  const int lcol = lane & 15;
  const int lr4 = (lane >> 4) * 4;
#pragma unroll
  for (int n = 0; n < 8; ++n) {
    int col = wid * 128 + n * 16 + lcol;
    float bv = bias[col];
#pragma unroll
    for (int j = 0; j < 4; ++j) {
      int row = bm + lr4 + j;
      float t = acc[n][j] + bv + Rsd[(size_t)row * D_ + col];
      acc[n][j] = t;
    }
  }

  // ---- LN pass 1 ----
  {
    float s0[4] = {}, s1[4] = {};
#pragma unroll
    for (int n = 0; n < 8; ++n)
#pragma unroll
      for (int j = 0; j < 4; ++j) {
        float v = acc[n][j];
        s0[j] += v; s1[j] += v * v;
      }
#pragma unroll
    for (int off = 1; off < 16; off <<= 1)
#pragma unroll
      for (int j = 0; j < 4; ++j) {
        s0[j] += __shfl_xor(s0[j], off);
        s1[j] += __shfl_xor(s1[j], off);
      }
    if ((lane & 15) == 0) {
#pragma unroll
      for (int j = 0; j < 4; ++j) {
        wsum[wid][lr4 + j] = s0[j]; wss[wid][lr4 + j] = s1[j];
      }
    }
  }
  __syncthreads();
  if (tid < 16) {
    float S  = wsum[0][tid] + wsum[1][tid] + wsum[2][tid] + wsum[3][tid];
    float SS = wss[0][tid] + wss[1][tid] + wss[2][tid] + wss[3][tid];
    float mu = S * (1.0f / D_);
    float var = SS * (1.0f / D_) - mu * mu;
    if (var < 0.f) var = 0.f;
    mu_s[tid] = mu; rs_s[tid] = rsqrtf(var + 1e-5f);
  }
  __syncthreads();

  float gg[8], bv2[8];
#pragma unroll
  for (int n = 0; n < 8; ++n) {
    int col = wid * 128 + n * 16 + lcol;
    gg[n] = g1[col]; bv2[n] = b1[col];
  }
#pragma unroll
  for (int n = 0; n < 8; ++n) {
    int col = wid * 128 + n * 16 + lcol;
#pragma unroll
    for (int j = 0; j < 4; ++j) {
      int r = lr4 + j;
      int row = bm + r;
      float ln = (acc[n][j] - mu_s[r]) * rs_s[r] * gg[n] + bv2[n];
      Xout[(size_t)row * D_ + col] = ln;
      acc[n][j] = ln;
    }
  }

  if (MODE == 1) {
    // ---- LN pass 2 on LN1 output ----
    __syncthreads();
    {
      float s0[4] = {}, s1[4] = {};
#pragma unroll
      for (int n = 0; n < 8; ++n)
#pragma unroll
        for (int j = 0; j < 4; ++j) {
          float v = acc[n][j];
          s0[j] += v; s1[j] += v * v;
        }
#pragma unroll
      for (int off = 1; off < 16; off <<= 1)
#pragma unroll
        for (int j = 0; j < 4; ++j) {
          s0[j] += __shfl_xor(s0[j], off);
          s1[j] += __shfl_xor(s1[j], off);
        }
      if ((lane & 15) == 0) {
#pragma unroll
        for (int j = 0; j < 4; ++j) {
          wsum[wid][lr4 + j] = s0[j]; wss[wid][lr4 + j] = s1[j];
        }
      }
    }
    __syncthreads();
    if (tid < 16) {
      float S  = wsum[0][tid] + wsum[1][tid] + wsum[2][tid] + wsum[3][tid];
      float SS = wss[0][tid] + wss[1][tid] + wss[2][tid] + wss[3][tid];
      float mu = S * (1.0f / D_);
      float var = SS * (1.0f / D_) - mu * mu;
      if (var < 0.f) var = 0.f;
      mu_s[tid] = mu; rs_s[tid] = rsqrtf(var + 1e-5f);
    }
    __syncthreads();
#pragma unroll
    for (int n = 0; n < 8; ++n) {
      int col = wid * 128 + n * 16 + lcol;
      gg[n] = g2[col]; bv2[n] = b2[col];
    }
#pragma unroll
    for (int n = 0; n < 8; ++n) {
      int col = wid * 128 + n * 16 + lcol;
#pragma unroll
      for (int j = 0; j < 4; ++j) {
        int r = lr4 + j;
        int row = bm + r;
        float ln = (acc[n][j] - mu_s[r]) * rs_s[r] * gg[n] + bv2[n];
        OutBf[(size_t)row * D_ + col] = f2bf(ln);
      }
    }
  }
}

// ---------------------------------------------------------------------------
// Block-diagonal attention reading fused QKV (stride 1536), vectorized loads.
// One block per (b, seg); wave h = head h. Segment rows: {s, 256+4s..+3}.
// ---------------------------------------------------------------------------
#define QLD 516
__global__ __launch_bounds__(256)
void attn_k(const u16* __restrict__ QKV, u16* __restrict__ O) {
  int bs = blockIdx.x;
  int b = bs >> 8, s = bs & 255;
  __shared__ float Qs[5][QLD];
  __shared__ float Ks[5][QLD];
  __shared__ float Vs[5][QLD];
  __shared__ float P[H_][5][5];
  int tid = threadIdx.x;
  const float scale = 0.08838834764831845f;
  int rows[5];
  rows[0] = s;
#pragma unroll
  for (int i = 1; i < 5; ++i) rows[i] = R_ + 4 * s + (i - 1);
  for (int idx = tid; idx < 960; idx += 256) {
    int mtx = idx / 320;
    int rem = idx - mtx * 320;
    int i = rem >> 6, c8 = rem & 63;
    size_t base = ((size_t)b * TOT_ + rows[i]) * CH_ + mtx * 512 + c8 * 8;
    bf16x8 v = *(const bf16x8*)(QKV + base);
    float* dst = (mtx == 0) ? &Qs[i][c8 * 8] : (mtx == 1 ? &Ks[i][c8 * 8] : &Vs[i][c8 * 8]);
    if (mtx == 0) {
#pragma unroll
      for (int t = 0; t < 8; ++t) dst[t] = bf2f((u16)v[t]) * scale;
    } else {
#pragma unroll
      for (int t = 0; t < 8; ++t) dst[t] = bf2f((u16)v[t]);
    }
  }
  __syncthreads();
  int h = tid >> 6, lane = tid & 63;
  if (lane < 25) {
    int i = lane / 5, j = lane % 5;
    float sum = 0.f;
    const float* qp = &Qs[i][h * DH_];
    const float* kp = &Ks[j][h * DH_];
#pragma unroll 8
    for (int d = 0; d < DH_; ++d) sum += qp[d] * kp[d];
    P[h][i][j] = sum;
  }
  __syncthreads();
  if (lane < 5) {
    int i = lane;
    float m = P[h][i][0];
#pragma unroll
    for (int j = 1; j < 5; ++j) m = fmaxf(m, P[h][i][j]);
    float e[5], ssum = 0.f;
#pragma unroll
    for (int j = 0; j < 5; ++j) { e[j] = __expf(P[h][i][j] - m); ssum += e[j]; }
    float inv = 1.0f / ssum;
#pragma unroll
    for (int j = 0; j < 5; ++j) P[h][i][j] = e[j] * inv;
  }
  __syncthreads();
  for (int idx = lane; idx < 5 * DH_; idx += 64) {
    int i = idx >> 7, d = idx & (DH_ - 1);
    float o = 0.f;
#pragma unroll
    for (int j = 0; j < 5; ++j) o += P[h][i][j] * Vs[j][h * DH_ + d];
    O[((size_t)b * TOT_ + rows[i]) * D_ + h * DH_ + d] = f2bf(o);
  }
}

// ---------------------------------------------------------------------------
// mean over the 1024 u rows -> (B, D), two stages.
// ---------------------------------------------------------------------------
__global__ __launch_bounds__(256)
void mean_part_k(const float* __restrict__ X, float* __restrict__ part) {
  int d = blockIdx.x * 256 + threadIdx.x;
  int jc = blockIdx.y;
  int b = blockIdx.z;
  float acc = 0.f;
  const float* base = X + ((size_t)b * TOT_ + R_ + jc * 128) * D_ + d;
  for (int j = 0; j < 128; ++j) acc += base[(size_t)j * D_];
  part[((size_t)b * 8 + jc) * D_ + d] = acc;
}

__global__ __launch_bounds__(256)
void mean_final_k(const float* __restrict__ part, float* __restrict__ out) {
  int i = blockIdx.x * 256 + threadIdx.x;
  int b = i >> 9, d = i & (D_ - 1);
  float acc = 0.f;
#pragma unroll
  for (int c = 0; c < 8; ++c) acc += part[((size_t)b * 8 + c) * D_ + d];
  out[i] = acc * (1.0f / U_);
}

// ---------------------------------------------------------------------------
// Launch. Workspace layout (byte offsets):
//   X      @ 0          fp32 20,971,520
//   LNbuf  @ 20971520   bf16 10,485,760
//   QKV    @ 31457280   bf16 31,457,280
//   ATT    @ 62914560   bf16 10,485,760
//   H      @ 83886080   bf16  2,621,440
//   part   @ 86507520   fp32    131,072
//   WQKVb  @ 86638592   bf16  6,291,456
//   Wob    @ 92930048   bf16  2,097,152
//   W1b    @ 95027200   bf16    524,288
//   W2b    @ 95551488   bf16    524,288
//   bQKV   @ 96075776   fp32     24,576
// ---------------------------------------------------------------------------
extern "C" void kernel_launch(void* const* d_in, const int* in_sizes, int n_in,
                              void* d_out, int out_size, void* d_ws, size_t ws_size,
                              hipStream_t stream) {
  const float* x      = (const float*)d_in[0];
  const float* Wq     = (const float*)d_in[1];
  const float* bq     = (const float*)d_in[2];
  const float* Wkv    = (const float*)d_in[3];
  const float* bkv    = (const float*)d_in[4];
  const float* Wo     = (const float*)d_in[5];
  const float* bo     = (const float*)d_in[6];
  const float* W1     = (const float*)d_in[7];
  const float* b1     = (const float*)d_in[8];
  const float* W2     = (const float*)d_in[9];
  const float* b2     = (const float*)d_in[10];
  const float* ln_in_g  = (const float*)d_in[11];
  const float* ln_in_b  = (const float*)d_in[12];
  const float* ff_ln_g  = (const float*)d_in[13];
  const float* ff_ln_b  = (const float*)d_in[14];
  const float* ln_out_g = (const float*)d_in[15];
  const float* ln_out_b = (const float*)d_in[16];
  float* out = (float*)d_out;

  char* wsb = (char*)d_ws;
  float* X     = (float*)wsb;
  u16*   LNbuf = (u16*)(wsb + 20971520);
  u16*   QKV   = (u16*)(wsb + 31457280);
  u16*   ATT   = (u16*)(wsb + 62914560);
  u16*   Hb    = (u16*)(wsb + 83886080);
  float* part  = (float*)(wsb + 86507520);
  u16*   WQKVb = (u16*)(wsb + 86638592);
  u16*   Wob   = (u16*)(wsb + 92930048);
  u16*   W1b   = (u16*)(wsb + 95027200);
  u16*   W2b   = (u16*)(wsb + 95551488);
  float* bQKV  = (float*)(wsb + 96075776);

  cvt_all_k<<<4614, 256, 0, stream>>>(Wq, Wkv, Wo, W1, W2, bq, bkv,
                                      WQKVb, Wob, W1b, W2b, bQKV);
  gather_ln_k<<<M_, 256, 0, stream>>>(x, ln_in_g, ln_in_b, X, LNbuf);

  for (int l = 0; l < L_; ++l) {
    const u16* WQKV_l = WQKVb + (size_t)l * CH_ * D_;
    const u16* Wo_l   = Wob   + (size_t)l * D_ * D_;
    const u16* W1_l   = W1b   + (size_t)l * FFN_ * D_;
    const u16* W2_l   = W2b   + (size_t)l * D_ * FFN_;
    const float* bQKV_l = bQKV + (size_t)l * CH_;
    const float* bo_l = bo + (size_t)l * D_;
    const float* b1_l = b1 + (size_t)l * FFN_;
    const float* b2_l = b2 + (size_t)l * D_;

    // QKV = LNbuf @ WQKV^T + bQKV
    gemm_qkv<<<960, 256, 0, stream>>>(LNbuf, WQKV_l, bQKV_l, QKV);

    // attention -> ATT
    attn_k<<<B_ * NSEG_, 256, 0, stream>>>(QKV, ATT);

    // X += ATT @ Wo^T + bo   (64x128 tiles, grid 640)
    gemm_oproj<<<640, 256, 0, stream>>>(ATT, Wo_l, bo_l, X);

    // H = relu(LN_ff(X) @ W1^T + b1)   (LN in prologue)
    ffn1_ln<<<M_ / 16, 256, 0, stream>>>(
        X, ff_ln_g + l * D_, ff_ln_b + l * D_, W1_l, b1_l, Hb);

    // X = LN_out(H @ W2^T + b2 + X); LNbuf = LN_in[l+1](X) if l<3
    if (l < L_ - 1) {
      gemm_row_ln<1><<<M_ / 16, 256, 0, stream>>>(
          Hb, W2_l, b2_l, X, X,
          ln_out_g + l * D_, ln_out_b + l * D_,
          ln_in_g + (l + 1) * D_, ln_in_b + (l + 1) * D_, LNbuf, FFN_);
    } else {
      gemm_row_ln<2><<<M_ / 16, 256, 0, stream>>>(
          Hb, W2_l, b2_l, X, X,
          ln_out_g + l * D_, ln_out_b + l * D_,
          nullptr, nullptr, nullptr, FFN_);
    }
  }

  mean_part_k<<<dim3(2, 8, 8), 256, 0, stream>>>(X, part);
  mean_final_k<<<(B_ * D_) / 256, 256, 0, stream>>>(part, out);
}

// Round 11
// 388.186 us; speedup vs baseline: 1.0454x; 1.0454x over previous
//
#include <hip/hip_runtime.h>
#include <cstdint>
#include <cstddef>

// Problem constants
#define D_    512
#define H_    4
#define DH_   128
#define FFN_  128
#define L_    4
#define B_    8
#define T_    1025
#define U_    1024
#define NSEG_ 256
#define R_    256
#define TOT_  1280            // R + U
#define M_    (B_*TOT_)       // 10240 rows
#define CH_   1536            // QKV channels

typedef __attribute__((ext_vector_type(8))) short bf16x8;
typedef __attribute__((ext_vector_type(4))) float f32x4;
typedef unsigned short u16;

__device__ __forceinline__ u16 f2bf(float f) {
  unsigned u = __builtin_bit_cast(unsigned, f);
  u += 0x7fff + ((u >> 16) & 1);           // round-to-nearest-even
  return (u16)(u >> 16);
}
__device__ __forceinline__ float bf2f(u16 h) {
  unsigned u = ((unsigned)h) << 16;
  return __builtin_bit_cast(float, u);
}

__device__ __forceinline__ void gload_lds16(const void* g, void* l) {
  __builtin_amdgcn_global_load_lds(
      (const __attribute__((address_space(1))) unsigned*)g,
      (__attribute__((address_space(3))) unsigned*)l, 16, 0, 0);
}

// ---------------------------------------------------------------------------
// one-shot weight conversion / packing:
//   WQKVb[l][1536][512] bf16  (rows 0-511 = Wq[l], 512-1535 = Wkv[l])
//   Wob, W1b, W2b bf16 straight copies;  bQKV[l][1536] fp32 (bq|bkv)
// ---------------------------------------------------------------------------
__global__ __launch_bounds__(256)
void cvt_all_k(const float* __restrict__ Wq, const float* __restrict__ Wkv,
               const float* __restrict__ Wo, const float* __restrict__ W1,
               const float* __restrict__ W2, const float* __restrict__ bq,
               const float* __restrict__ bkv,
               u16* __restrict__ WQKVb, u16* __restrict__ Wob,
               u16* __restrict__ W1b, u16* __restrict__ W2b,
               float* __restrict__ bQKV) {
  int i4 = blockIdx.x * 256 + threadIdx.x;
  if (i4 < 786432) {                        // WQKV: 3,145,728 elems
    int e = i4 * 4;
    int l = e / 786432;
    int rem = e - l * 786432;
    int n = rem >> 9, k = rem & 511;
    const float* src = (n < 512) ? (Wq + (size_t)l * 262144 + n * 512 + k)
                                 : (Wkv + (size_t)l * 524288 + (n - 512) * 512 + k);
    float4 v = *(const float4*)src;
    ushort4 o; o.x = f2bf(v.x); o.y = f2bf(v.y); o.z = f2bf(v.z); o.w = f2bf(v.w);
    *(ushort4*)(WQKVb + e) = o;
  } else if (i4 < 1048576) {                // Wo
    int e = (i4 - 786432) * 4;
    float4 v = *(const float4*)(Wo + e);
    ushort4 o; o.x = f2bf(v.x); o.y = f2bf(v.y); o.z = f2bf(v.z); o.w = f2bf(v.w);
    *(ushort4*)(Wob + e) = o;
  } else if (i4 < 1114112) {                // W1
    int e = (i4 - 1048576) * 4;
    float4 v = *(const float4*)(W1 + e);
    ushort4 o; o.x = f2bf(v.x); o.y = f2bf(v.y); o.z = f2bf(v.z); o.w = f2bf(v.w);
    *(ushort4*)(W1b + e) = o;
  } else if (i4 < 1179648) {                // W2
    int e = (i4 - 1114112) * 4;
    float4 v = *(const float4*)(W2 + e);
    ushort4 o; o.x = f2bf(v.x); o.y = f2bf(v.y); o.z = f2bf(v.z); o.w = f2bf(v.w);
    *(ushort4*)(W2b + e) = o;
  } else if (i4 < 1181184) {                // bias: 6144 elems
    int e = (i4 - 1179648) * 4;
    int l = e / 1536, n = e - l * 1536;
#pragma unroll
    for (int t = 0; t < 4; ++t) {
      int nn = n + t;
      bQKV[e + t] = (nn < 512) ? bq[l * 512 + nn] : bkv[l * 1024 + (nn - 512)];
    }
  }
}

// ---------------------------------------------------------------------------
// gather + LN-in(layer 0): builds X (fp32 residual) and LNbuf (bf16)
// ---------------------------------------------------------------------------
__global__ __launch_bounds__(256)
void gather_ln_k(const float* __restrict__ x, const float* __restrict__ g,
                 const float* __restrict__ bb, float* __restrict__ X,
                 u16* __restrict__ LNb) {
  int row = blockIdx.x;
  int tid = threadIdx.x;
  int b = row / TOT_, p = row % TOT_;
  int t = (p < R_) ? ((p < R_ - 1) ? 4 * (p + 1) : (T_ - 1)) : (p - R_);
  const float* xr = x + ((size_t)b * T_ + t) * D_;
  float e0 = xr[tid], e1 = xr[tid + 256];
  X[(size_t)row * D_ + tid] = e0;
  X[(size_t)row * D_ + tid + 256] = e1;
  float s = e0 + e1, ss = e0 * e0 + e1 * e1;
#pragma unroll
  for (int off = 32; off > 0; off >>= 1) {
    s  += __shfl_down(s, off);
    ss += __shfl_down(ss, off);
  }
  __shared__ float red[10];
  int wid = tid >> 6, lane = tid & 63;
  if (lane == 0) { red[wid] = s; red[4 + wid] = ss; }
  __syncthreads();
  if (tid == 0) {
    float S = red[0] + red[1] + red[2] + red[3];
    float SS = red[4] + red[5] + red[6] + red[7];
    float mu = S * (1.0f / D_);
    float var = SS * (1.0f / D_) - mu * mu;
    if (var < 0.f) var = 0.f;
    red[8] = mu; red[9] = rsqrtf(var + 1e-5f);
  }
  __syncthreads();
  float mu = red[8], rs = red[9];
  u16* yr = LNb + (size_t)row * D_;
  yr[tid]       = f2bf((e0 - mu) * rs * g[tid]       + bb[tid]);
  yr[tid + 256] = f2bf((e1 - mu) * rs * g[tid + 256] + bb[tid + 256]);
}

// ---------------------------------------------------------------------------
// bf16 MFMA GEMM, m97-style (128x128 tile, BK=32, 4 waves), XCD-swizzled.
// QKV projection: M=10240, N=1536, K=512. xcd=bid&7 owns 10 row-stripes
// x 12 col-blocks -> A chunk 1.28MB L2-resident per XCD.
// ---------------------------------------------------------------------------
#define GBK 32

__global__ __launch_bounds__(256)
void gemm_qkv(const u16* __restrict__ A, const u16* __restrict__ Bw,
              const float* __restrict__ bias, u16* __restrict__ Cout) {
  __shared__ __align__(16) u16 As[128 * GBK];
  __shared__ __align__(16) u16 Bs[128 * GBK];
  const int tid = threadIdx.x;
  const int wid = tid >> 6;
  const int lane = tid & 63;
  const int bid = blockIdx.x;
  const int xcd = bid & 7;
  const int t = bid >> 3;                 // 0..119
  const int cb = t % 12;
  const int rb = xcd * 10 + t / 12;
  const int bm = rb * 128;
  const int bn = cb * 128;
  const int wr = wid >> 1, wc = wid & 1;

  const int srow = tid >> 2;
  const int skoff = (tid & 3) << 3;

  f32x4 acc[4][4] = {};

  const u16* Ag0 = A  + (size_t)(bm + srow)      * D_ + skoff;
  const u16* Ag1 = A  + (size_t)(bm + 64 + srow) * D_ + skoff;
  const u16* Bg0 = Bw + (size_t)(bn + srow)      * D_ + skoff;
  const u16* Bg1 = Bw + (size_t)(bn + 64 + srow) * D_ + skoff;
  u16* AsW0 = &As[(size_t)(wid * 16)      * GBK];
  u16* AsW1 = &As[(size_t)(64 + wid * 16) * GBK];
  u16* BsW0 = &Bs[(size_t)(wid * 16)      * GBK];
  u16* BsW1 = &Bs[(size_t)(64 + wid * 16) * GBK];

  const int lrow = lane & 15;
  const int lko  = (lane >> 4) * 16;

  for (int k0 = 0; k0 < D_; k0 += GBK) {
    __syncthreads();
    gload_lds16(Ag0 + k0, AsW0);
    gload_lds16(Ag1 + k0, AsW1);
    gload_lds16(Bg0 + k0, BsW0);
    gload_lds16(Bg1 + k0, BsW1);
    __syncthreads();

    bf16x8 afrag[4], bfrag[4];
#pragma unroll
    for (int m = 0; m < 4; ++m) {
      int row = wr * 64 + m * 16 + lrow;
      afrag[m] = *(const bf16x8*)((const char*)As + row * (GBK * 2) + lko);
    }
#pragma unroll
    for (int n = 0; n < 4; ++n) {
      int col = wc * 64 + n * 16 + lrow;
      bfrag[n] = *(const bf16x8*)((const char*)Bs + col * (GBK * 2) + lko);
    }
#pragma unroll
    for (int m = 0; m < 4; ++m)
#pragma unroll
      for (int n = 0; n < 4; ++n)
        acc[m][n] = __builtin_amdgcn_mfma_f32_16x16x32_bf16(
            afrag[m], bfrag[n], acc[m][n], 0, 0, 0);
  }

  const int lcol  = lane & 15;
  const int lrow4 = (lane >> 4) * 4;
#pragma unroll
  for (int m = 0; m < 4; ++m) {
    int rowbase = bm + wr * 64 + m * 16 + lrow4;
#pragma unroll
    for (int n = 0; n < 4; ++n) {
      int col = bn + wc * 64 + n * 16 + lcol;
      float bv = bias[col];
#pragma unroll
      for (int j = 0; j < 4; ++j) {
        int row = rowbase + j;
        Cout[(size_t)row * CH_ + col] = f2bf(acc[m][n][j] + bv);
      }
    }
  }
}

// ---------------------------------------------------------------------------
// O-proj: pure N-tiled GEMM + residual, fp32 out (in-place X).
// 128x128 tile, 4 waves, grid 320 = 8 xcd x 4 cb x 10 rb. (round-9 version)
// ---------------------------------------------------------------------------
__global__ __launch_bounds__(256)
void gemm_oproj(const u16* __restrict__ A, const u16* __restrict__ Bw,
                const float* __restrict__ bias, float* __restrict__ Xio) {
  __shared__ __align__(16) u16 As[128 * GBK];
  __shared__ __align__(16) u16 Bs[128 * GBK];
  const int tid = threadIdx.x;
  const int wid = tid >> 6;
  const int lane = tid & 63;
  const int bid = blockIdx.x;
  const int xcd = bid & 7;
  const int t = bid >> 3;                 // 0..39
  const int cb = t & 3;
  const int rb = xcd * 10 + (t >> 2);
  const int bm = rb * 128;
  const int bn = cb * 128;
  const int wr = wid >> 1, wc = wid & 1;

  const int srow = tid >> 2;
  const int skoff = (tid & 3) << 3;

  f32x4 acc[4][4] = {};

  const u16* Ag0 = A  + (size_t)(bm + srow)      * D_ + skoff;
  const u16* Ag1 = A  + (size_t)(bm + 64 + srow) * D_ + skoff;
  const u16* Bg0 = Bw + (size_t)(bn + srow)      * D_ + skoff;
  const u16* Bg1 = Bw + (size_t)(bn + 64 + srow) * D_ + skoff;
  u16* AsW0 = &As[(size_t)(wid * 16)      * GBK];
  u16* AsW1 = &As[(size_t)(64 + wid * 16) * GBK];
  u16* BsW0 = &Bs[(size_t)(wid * 16)      * GBK];
  u16* BsW1 = &Bs[(size_t)(64 + wid * 16) * GBK];

  const int lrow = lane & 15;
  const int lko  = (lane >> 4) * 16;

  for (int k0 = 0; k0 < D_; k0 += GBK) {
    __syncthreads();
    gload_lds16(Ag0 + k0, AsW0);
    gload_lds16(Ag1 + k0, AsW1);
    gload_lds16(Bg0 + k0, BsW0);
    gload_lds16(Bg1 + k0, BsW1);
    __syncthreads();

    bf16x8 afrag[4], bfrag[4];
#pragma unroll
    for (int m = 0; m < 4; ++m) {
      int row = wr * 64 + m * 16 + lrow;
      afrag[m] = *(const bf16x8*)((const char*)As + row * (GBK * 2) + lko);
    }
#pragma unroll
    for (int n = 0; n < 4; ++n) {
      int col = wc * 64 + n * 16 + lrow;
      bfrag[n] = *(const bf16x8*)((const char*)Bs + col * (GBK * 2) + lko);
    }
#pragma unroll
    for (int m = 0; m < 4; ++m)
#pragma unroll
      for (int n = 0; n < 4; ++n)
        acc[m][n] = __builtin_amdgcn_mfma_f32_16x16x32_bf16(
            afrag[m], bfrag[n], acc[m][n], 0, 0, 0);
  }

  const int lcol  = lane & 15;
  const int lrow4 = (lane >> 4) * 4;
#pragma unroll
  for (int m = 0; m < 4; ++m) {
    int rowbase = bm + wr * 64 + m * 16 + lrow4;
#pragma unroll
    for (int n = 0; n < 4; ++n) {
      int col = bn + wc * 64 + n * 16 + lcol;
      float bv = bias[col];
#pragma unroll
      for (int j = 0; j < 4; ++j) {
        size_t idx = (size_t)(rowbase + j) * D_ + col;
        Xio[idx] = acc[m][n][j] + bv + Xio[idx];
      }
    }
  }
}

// ---------------------------------------------------------------------------
// Fused FFN: LN_ff (register prologue) -> FFN1(relu, H in regs->LDS) ->
// FFN2 + residual + LN_out (+ LN_in next). 16-row tiles, grid 640.
// Phase A = old ffn1_ln; H handed through 4KB swizzled LDS (overlays Aln);
// phase B = old gemm_row_ln with A-operand from LDS. Saves the H global
// roundtrip, the row_ln A-staging, and one dispatch per layer.
// MODE 1 (l<3): LN1 -> Xout fp32; LN2 -> OutBf bf16.   MODE 2: LN1 only.
// ---------------------------------------------------------------------------
template <int MODE>
__global__ __launch_bounds__(256)
void ffn_fused(const float* __restrict__ X,
               const float* __restrict__ gff, const float* __restrict__ bff,
               const u16* __restrict__ W1, const float* __restrict__ b1,
               const u16* __restrict__ W2, const float* __restrict__ b2,
               const float* __restrict__ g1, const float* __restrict__ b1o,
               const float* __restrict__ g2, const float* __restrict__ b2i,
               float* __restrict__ Xout, u16* __restrict__ OutBf) {
  __shared__ __align__(16) u16 Bs[512 * 32];    // 32KB: W1 (first 8KB) / W2
  __shared__ __align__(16) u16 Aln[16 * 512];   // 16KB swizzled; Hs overlays
  __shared__ float wsum[4][16], wss[4][16], mu_s[16], rs_s[16];
  u16* Hs = Aln;                                // 4KB overlay (post phase A)
  const int tid = threadIdx.x;
  const int wid = tid >> 6, lane = tid & 63;
  const int bm = blockIdx.x * 16;
  const int r  = tid >> 4;            // 0..15 row in tile
  const int jj = tid & 15;            // 16 lanes per row

  // ---- LN_ff prologue (in registers) ----
  {
    const float* xr = X + (size_t)(bm + r) * D_ + jj * 32;
    float v[32];
    float s = 0.f, ss = 0.f;
#pragma unroll
    for (int i = 0; i < 8; ++i) {
      float4 q = *(const float4*)(xr + i * 4);
      v[i * 4 + 0] = q.x; v[i * 4 + 1] = q.y;
      v[i * 4 + 2] = q.z; v[i * 4 + 3] = q.w;
      s  += q.x + q.y + q.z + q.w;
      ss += q.x * q.x + q.y * q.y + q.z * q.z + q.w * q.w;
    }
#pragma unroll
    for (int off = 1; off < 16; off <<= 1) {
      s  += __shfl_xor(s, off);
      ss += __shfl_xor(ss, off);
    }
    float mu = s * (1.0f / D_);
    float var = ss * (1.0f / D_) - mu * mu;
    if (var < 0.f) var = 0.f;
    float rs = rsqrtf(var + 1e-5f);
    char* Ab = (char*)Aln;
#pragma unroll
    for (int i = 0; i < 8; ++i) {
      int c0 = jj * 32 + i * 4;
      float4 g4 = *(const float4*)(gff + c0);
      float4 b4 = *(const float4*)(bff + c0);
      ushort4 o;
      o.x = f2bf((v[i * 4 + 0] - mu) * rs * g4.x + b4.x);
      o.y = f2bf((v[i * 4 + 1] - mu) * rs * g4.y + b4.y);
      o.z = f2bf((v[i * 4 + 2] - mu) * rs * g4.z + b4.z);
      o.w = f2bf((v[i * 4 + 3] - mu) * rs * g4.w + b4.w);
      int byteoff = (r * 1024 + c0 * 2) ^ ((r & 7) << 4);
      *(ushort4*)(Ab + byteoff) = o;
    }
  }
  __syncthreads();

  // ---- phase A: H = relu(LN_ff @ W1^T + b1), H in registers ----
  const int lrow = lane & 15;
  const int lko  = (lane >> 4) << 4;   // bytes
  const int l4 = lane >> 2;
  const int k8 = (lane & 3) << 3;
  f32x4 accA[2] = {};

  for (int k0 = 0; k0 < D_; k0 += 32) {
    if (k0) __syncthreads();
#pragma unroll
    for (int p = 0; p < 2; ++p) {
      int rowb = wid * 32 + p * 16 + l4;
      gload_lds16(W1 + (size_t)rowb * D_ + k0 + k8,
                  (char*)Bs + (wid * 32 + p * 16) * 64);
    }
    __syncthreads();
    bf16x8 af = *(const bf16x8*)((const char*)Aln +
                  ((lrow * 1024 + k0 * 2 + lko) ^ ((lrow & 7) << 4)));
    bf16x8 bf[2];
#pragma unroll
    for (int n = 0; n < 2; ++n)
      bf[n] = *(const bf16x8*)((const char*)Bs + (wid * 32 + n * 16 + lrow) * 64 + lko);
#pragma unroll
    for (int n = 0; n < 2; ++n)
      accA[n] = __builtin_amdgcn_mfma_f32_16x16x32_bf16(af, bf[n], accA[n], 0, 0, 0);
  }

  const int lcol = lane & 15;
  const int lr4 = (lane >> 4) * 4;
  __syncthreads();                     // all Aln/Bs reads complete

  // ---- hand H to LDS (bias + relu, swizzled; overlays Aln) ----
#pragma unroll
  for (int n = 0; n < 2; ++n) {
    int col = wid * 32 + n * 16 + lcol;
    float bv = b1[col];
#pragma unroll
    for (int j = 0; j < 4; ++j) {
      int rr = lr4 + j;
      float hv = fmaxf(accA[n][j] + bv, 0.f);
      int byteoff = (rr * 256 + col * 2) ^ ((rr & 7) << 4);
      *(u16*)((char*)Hs + byteoff) = f2bf(hv);
    }
  }

  // ---- phase B: FFN2 + residual + LN_out (+ LN_in) ----
  f32x4 acc[8] = {};
  for (int k0 = 0; k0 < FFN_; k0 += 32) {
    __syncthreads();                   // k0=0: Hs visible; else: reads done
#pragma unroll
    for (int p = 0; p < 8; ++p) {
      int row = wid * 128 + p * 16 + l4;
      gload_lds16(W2 + (size_t)row * FFN_ + k0 + k8,
                  (char*)Bs + (wid * 128 + p * 16) * 64);
    }
    __syncthreads();

    bf16x8 af = *(const bf16x8*)((const char*)Hs +
                  ((lrow * 256 + k0 * 2 + lko) ^ ((lrow & 7) << 4)));
    bf16x8 bf[8];
#pragma unroll
    for (int n = 0; n < 8; ++n)
      bf[n] = *(const bf16x8*)((const char*)Bs + (wid * 128 + n * 16 + lrow) * 64 + lko);
#pragma unroll
    for (int n = 0; n < 8; ++n)
      acc[n] = __builtin_amdgcn_mfma_f32_16x16x32_bf16(af, bf[n], acc[n], 0, 0, 0);
  }

  // ---- bias + residual ----
#pragma unroll
  for (int n = 0; n < 8; ++n) {
    int col = wid * 128 + n * 16 + lcol;
    float bv = b2[col];
#pragma unroll
    for (int j = 0; j < 4; ++j) {
      int row = bm + lr4 + j;
      acc[n][j] = acc[n][j] + bv + X[(size_t)row * D_ + col];
    }
  }

  // ---- LN pass 1 (ln_out) ----
  {
    float s0[4] = {}, s1[4] = {};
#pragma unroll
    for (int n = 0; n < 8; ++n)
#pragma unroll
      for (int j = 0; j < 4; ++j) {
        float v = acc[n][j];
        s0[j] += v; s1[j] += v * v;
      }
#pragma unroll
    for (int off = 1; off < 16; off <<= 1)
#pragma unroll
      for (int j = 0; j < 4; ++j) {
        s0[j] += __shfl_xor(s0[j], off);
        s1[j] += __shfl_xor(s1[j], off);
      }
    if ((lane & 15) == 0) {
#pragma unroll
      for (int j = 0; j < 4; ++j) {
        wsum[wid][lr4 + j] = s0[j]; wss[wid][lr4 + j] = s1[j];
      }
    }
  }
  __syncthreads();
  if (tid < 16) {
    float S  = wsum[0][tid] + wsum[1][tid] + wsum[2][tid] + wsum[3][tid];
    float SS = wss[0][tid] + wss[1][tid] + wss[2][tid] + wss[3][tid];
    float mu = S * (1.0f / D_);
    float var = SS * (1.0f / D_) - mu * mu;
    if (var < 0.f) var = 0.f;
    mu_s[tid] = mu; rs_s[tid] = rsqrtf(var + 1e-5f);
  }
  __syncthreads();

  float gg[8], bv2[8];
#pragma unroll
  for (int n = 0; n < 8; ++n) {
    int col = wid * 128 + n * 16 + lcol;
    gg[n] = g1[col]; bv2[n] = b1o[col];
  }
#pragma unroll
  for (int n = 0; n < 8; ++n) {
    int col = wid * 128 + n * 16 + lcol;
#pragma unroll
    for (int j = 0; j < 4; ++j) {
      int rr = lr4 + j;
      int row = bm + rr;
      float ln = (acc[n][j] - mu_s[rr]) * rs_s[rr] * gg[n] + bv2[n];
      Xout[(size_t)row * D_ + col] = ln;
      acc[n][j] = ln;
    }
  }

  if (MODE == 1) {
    // ---- LN pass 2 (ln_in next layer) ----
    __syncthreads();
    {
      float s0[4] = {}, s1[4] = {};
#pragma unroll
      for (int n = 0; n < 8; ++n)
#pragma unroll
        for (int j = 0; j < 4; ++j) {
          float v = acc[n][j];
          s0[j] += v; s1[j] += v * v;
        }
#pragma unroll
      for (int off = 1; off < 16; off <<= 1)
#pragma unroll
        for (int j = 0; j < 4; ++j) {
          s0[j] += __shfl_xor(s0[j], off);
          s1[j] += __shfl_xor(s1[j], off);
        }
      if ((lane & 15) == 0) {
#pragma unroll
        for (int j = 0; j < 4; ++j) {
          wsum[wid][lr4 + j] = s0[j]; wss[wid][lr4 + j] = s1[j];
        }
      }
    }
    __syncthreads();
    if (tid < 16) {
      float S  = wsum[0][tid] + wsum[1][tid] + wsum[2][tid] + wsum[3][tid];
      float SS = wss[0][tid] + wss[1][tid] + wss[2][tid] + wss[3][tid];
      float mu = S * (1.0f / D_);
      float var = SS * (1.0f / D_) - mu * mu;
      if (var < 0.f) var = 0.f;
      mu_s[tid] = mu; rs_s[tid] = rsqrtf(var + 1e-5f);
    }
    __syncthreads();
#pragma unroll
    for (int n = 0; n < 8; ++n) {
      int col = wid * 128 + n * 16 + lcol;
      gg[n] = g2[col]; bv2[n] = b2i[col];
    }
#pragma unroll
    for (int n = 0; n < 8; ++n) {
      int col = wid * 128 + n * 16 + lcol;
#pragma unroll
      for (int j = 0; j < 4; ++j) {
        int rr = lr4 + j;
        int row = bm + rr;
        float ln = (acc[n][j] - mu_s[rr]) * rs_s[rr] * gg[n] + bv2[n];
        OutBf[(size_t)row * D_ + col] = f2bf(ln);
      }
    }
  }
}

// ---------------------------------------------------------------------------
// Block-diagonal attention reading fused QKV (stride 1536), vectorized loads.
// One block per (b, seg); wave h = head h. Segment rows: {s, 256+4s..+3}.
// ---------------------------------------------------------------------------
#define QLD 516
__global__ __launch_bounds__(256)
void attn_k(const u16* __restrict__ QKV, u16* __restrict__ O) {
  int bs = blockIdx.x;
  int b = bs >> 8, s = bs & 255;
  __shared__ float Qs[5][QLD];
  __shared__ float Ks[5][QLD];
  __shared__ float Vs[5][QLD];
  __shared__ float P[H_][5][5];
  int tid = threadIdx.x;
  const float scale = 0.08838834764831845f;
  int rows[5];
  rows[0] = s;
#pragma unroll
  for (int i = 1; i < 5; ++i) rows[i] = R_ + 4 * s + (i - 1);
  for (int idx = tid; idx < 960; idx += 256) {
    int mtx = idx / 320;
    int rem = idx - mtx * 320;
    int i = rem >> 6, c8 = rem & 63;
    size_t base = ((size_t)b * TOT_ + rows[i]) * CH_ + mtx * 512 + c8 * 8;
    bf16x8 v = *(const bf16x8*)(QKV + base);
    float* dst = (mtx == 0) ? &Qs[i][c8 * 8] : (mtx == 1 ? &Ks[i][c8 * 8] : &Vs[i][c8 * 8]);
    if (mtx == 0) {
#pragma unroll
      for (int t = 0; t < 8; ++t) dst[t] = bf2f((u16)v[t]) * scale;
    } else {
#pragma unroll
      for (int t = 0; t < 8; ++t) dst[t] = bf2f((u16)v[t]);
    }
  }
  __syncthreads();
  int h = tid >> 6, lane = tid & 63;
  if (lane < 25) {
    int i = lane / 5, j = lane % 5;
    float sum = 0.f;
    const float* qp = &Qs[i][h * DH_];
    const float* kp = &Ks[j][h * DH_];
#pragma unroll 8
    for (int d = 0; d < DH_; ++d) sum += qp[d] * kp[d];
    P[h][i][j] = sum;
  }
  __syncthreads();
  if (lane < 5) {
    int i = lane;
    float m = P[h][i][0];
#pragma unroll
    for (int j = 1; j < 5; ++j) m = fmaxf(m, P[h][i][j]);
    float e[5], ssum = 0.f;
#pragma unroll
    for (int j = 0; j < 5; ++j) { e[j] = __expf(P[h][i][j] - m); ssum += e[j]; }
    float inv = 1.0f / ssum;
#pragma unroll
    for (int j = 0; j < 5; ++j) P[h][i][j] = e[j] * inv;
  }
  __syncthreads();
  for (int idx = lane; idx < 5 * DH_; idx += 64) {
    int i = idx >> 7, d = idx & (DH_ - 1);
    float o = 0.f;
#pragma unroll
    for (int j = 0; j < 5; ++j) o += P[h][i][j] * Vs[j][h * DH_ + d];
    O[((size_t)b * TOT_ + rows[i]) * D_ + h * DH_ + d] = f2bf(o);
  }
}

// ---------------------------------------------------------------------------
// mean over the 1024 u rows -> (B, D), two stages.
// ---------------------------------------------------------------------------
__global__ __launch_bounds__(256)
void mean_part_k(const float* __restrict__ X, float* __restrict__ part) {
  int d = blockIdx.x * 256 + threadIdx.x;
  int jc = blockIdx.y;
  int b = blockIdx.z;
  float acc = 0.f;
  const float* base = X + ((size_t)b * TOT_ + R_ + jc * 128) * D_ + d;
  for (int j = 0; j < 128; ++j) acc += base[(size_t)j * D_];
  part[((size_t)b * 8 + jc) * D_ + d] = acc;
}

__global__ __launch_bounds__(256)
void mean_final_k(const float* __restrict__ part, float* __restrict__ out) {
  int i = blockIdx.x * 256 + threadIdx.x;
  int b = i >> 9, d = i & (D_ - 1);
  float acc = 0.f;
#pragma unroll
  for (int c = 0; c < 8; ++c) acc += part[((size_t)b * 8 + c) * D_ + d];
  out[i] = acc * (1.0f / U_);
}

// ---------------------------------------------------------------------------
// Launch. Workspace layout (byte offsets):
//   X      @ 0          fp32 20,971,520
//   LNbuf  @ 20971520   bf16 10,485,760
//   QKV    @ 31457280   bf16 31,457,280
//   ATT    @ 62914560   bf16 10,485,760
//   part   @ 86507520   fp32    131,072
//   WQKVb  @ 86638592   bf16  6,291,456
//   Wob    @ 92930048   bf16  2,097,152
//   W1b    @ 95027200   bf16    524,288
//   W2b    @ 95551488   bf16    524,288
//   bQKV   @ 96075776   fp32     24,576
// ---------------------------------------------------------------------------
extern "C" void kernel_launch(void* const* d_in, const int* in_sizes, int n_in,
                              void* d_out, int out_size, void* d_ws, size_t ws_size,
                              hipStream_t stream) {
  const float* x      = (const float*)d_in[0];
  const float* Wq     = (const float*)d_in[1];
  const float* bq     = (const float*)d_in[2];
  const float* Wkv    = (const float*)d_in[3];
  const float* bkv    = (const float*)d_in[4];
  const float* Wo     = (const float*)d_in[5];
  const float* bo     = (const float*)d_in[6];
  const float* W1     = (const float*)d_in[7];
  const float* b1     = (const float*)d_in[8];
  const float* W2     = (const float*)d_in[9];
  const float* b2     = (const float*)d_in[10];
  const float* ln_in_g  = (const float*)d_in[11];
  const float* ln_in_b  = (const float*)d_in[12];
  const float* ff_ln_g  = (const float*)d_in[13];
  const float* ff_ln_b  = (const float*)d_in[14];
  const float* ln_out_g = (const float*)d_in[15];
  const float* ln_out_b = (const float*)d_in[16];
  float* out = (float*)d_out;

  char* wsb = (char*)d_ws;
  float* X     = (float*)wsb;
  u16*   LNbuf = (u16*)(wsb + 20971520);
  u16*   QKV   = (u16*)(wsb + 31457280);
  u16*   ATT   = (u16*)(wsb + 62914560);
  float* part  = (float*)(wsb + 86507520);
  u16*   WQKVb = (u16*)(wsb + 86638592);
  u16*   Wob   = (u16*)(wsb + 92930048);
  u16*   W1b   = (u16*)(wsb + 95027200);
  u16*   W2b   = (u16*)(wsb + 95551488);
  float* bQKV  = (float*)(wsb + 96075776);

  cvt_all_k<<<4614, 256, 0, stream>>>(Wq, Wkv, Wo, W1, W2, bq, bkv,
                                      WQKVb, Wob, W1b, W2b, bQKV);
  gather_ln_k<<<M_, 256, 0, stream>>>(x, ln_in_g, ln_in_b, X, LNbuf);

  for (int l = 0; l < L_; ++l) {
    const u16* WQKV_l = WQKVb + (size_t)l * CH_ * D_;
    const u16* Wo_l   = Wob   + (size_t)l * D_ * D_;
    const u16* W1_l   = W1b   + (size_t)l * FFN_ * D_;
    const u16* W2_l   = W2b   + (size_t)l * D_ * FFN_;
    const float* bQKV_l = bQKV + (size_t)l * CH_;
    const float* bo_l = bo + (size_t)l * D_;
    const float* b1_l = b1 + (size_t)l * FFN_;
    const float* b2_l = b2 + (size_t)l * D_;

    // QKV = LNbuf @ WQKV^T + bQKV
    gemm_qkv<<<960, 256, 0, stream>>>(LNbuf, WQKV_l, bQKV_l, QKV);

    // attention -> ATT
    attn_k<<<B_ * NSEG_, 256, 0, stream>>>(QKV, ATT);

    // X += ATT @ Wo^T + bo   (128x128 tiles, grid 320 — round-9 version)
    gemm_oproj<<<320, 256, 0, stream>>>(ATT, Wo_l, bo_l, X);

    // fused FFN: LN_ff -> FFN1(relu) -> FFN2 + X + LN_out (+LN_in next)
    if (l < L_ - 1) {
      ffn_fused<1><<<M_ / 16, 256, 0, stream>>>(
          X, ff_ln_g + l * D_, ff_ln_b + l * D_,
          W1_l, b1_l, W2_l, b2_l,
          ln_out_g + l * D_, ln_out_b + l * D_,
          ln_in_g + (l + 1) * D_, ln_in_b + (l + 1) * D_,
          X, LNbuf);
    } else {
      ffn_fused<2><<<M_ / 16, 256, 0, stream>>>(
          X, ff_ln_g + l * D_, ff_ln_b + l * D_,
          W1_l, b1_l, W2_l, b2_l,
          ln_out_g + l * D_, ln_out_b + l * D_,
          nullptr, nullptr,
          X, nullptr);
    }
  }

  mean_part_k<<<dim3(2, 8, 8), 256, 0, stream>>>(X, part);
  mean_final_k<<<(B_ * D_) / 256, 256, 0, stream>>>(part, out);
}